// Round 2
// baseline (604.916 us; speedup 1.0000x reference)
//
#include <hip/hip_runtime.h>

// NodeFeat: out[n,d,c] (c stride 1, d stride 9, n stride 576), c = hop*3 + part
//   hop0: x * {1, rsqrt(deg), sqrt(deg)}
//   hop1: (1/deg) * spmm(hop0)
//   hop2: (1/deg) * spmm(hop1) - hop0
// R3 changes (edge-parallel waves):
//   - k_prop1/k_prop2: wave split into 4 groups of 16 lanes; each group owns a
//     different edge, each lane covers 4 features (vector loads: uint2 of bf16
//     for xb, uint4+uint2 for packed xs1). One gather instruction now covers 4
//     edges -> ~2.7x fewer VMEM instructions and ~2x fewer VALU per edge.
//   - per-node cross-group reduce: shfl_xor(16), shfl_xor(32) once per node.
//   - prop2 redistributes sums to lane=d (12 bpermutes/node) and keeps R1's
//     proven full-line 9-float epilogue store pattern.

static inline size_t ws_align(size_t x) { return (x + 255) & ~(size_t)255; }

__device__ inline float bf2f(unsigned short s) {
  return __uint_as_float(((unsigned)s) << 16);
}
__device__ inline unsigned short f2bf(float f) {
  unsigned u = __float_as_uint(f);
  unsigned r = u + 0x7fff + ((u >> 16) & 1);   // round-to-nearest-even
  return (unsigned short)(r >> 16);
}
__device__ inline float bflo(unsigned p) { return __uint_as_float(p << 16); }
__device__ inline float bfhi(unsigned p) { return __uint_as_float(p & 0xffff0000u); }
__device__ inline unsigned packbf(float a, float b) {
  return (unsigned)f2bf(a) | ((unsigned)f2bf(b) << 16);
}
__device__ inline float sel4(float u0, float u1, float u2, float u3, int k) {
  float a = (k & 1) ? u1 : u0;
  float b = (k & 1) ? u3 : u2;
  return (k & 2) ? b : a;
}

__global__ __launch_bounds__(256) void k_hist(const int* __restrict__ row,
                                              int* __restrict__ counts, int E) {
  int e = blockIdx.x * 256 + threadIdx.x;
  if (e < E) atomicAdd(&counts[row[e]], 1);
}

__global__ __launch_bounds__(1024) void k_blocksum(const int* __restrict__ counts,
                                                   int* __restrict__ partial, int N) {
  __shared__ int wsum[16];
  int t = threadIdx.x;
  int idx = blockIdx.x * 1024 + t;
  int v = (idx < N) ? counts[idx] : 0;
  for (int off = 32; off; off >>= 1) v += __shfl_down(v, off, 64);
  if ((t & 63) == 0) wsum[t >> 6] = v;
  __syncthreads();
  if (t == 0) {
    int s = 0;
#pragma unroll
    for (int k = 0; k < 16; ++k) s += wsum[k];
    partial[blockIdx.x] = s;
  }
}

__global__ void k_scanpartial(const int* __restrict__ partial,
                              int* __restrict__ pscan, int NB) {
  __shared__ int buf[1024];
  int t = threadIdx.x;
  for (int k = t; k < NB; k += blockDim.x) buf[k] = partial[k];
  __syncthreads();
  if (t == 0) {
    int run = 0;
    for (int k = 0; k < NB; ++k) { int v = buf[k]; buf[k] = run; run += v; }
  }
  __syncthreads();
  for (int k = t; k < NB; k += blockDim.x) pscan[k] = buf[k];
}

__global__ __launch_bounds__(1024) void k_scanapply(const int* __restrict__ counts,
    const int* __restrict__ pscan, int* __restrict__ offsets,
    int* __restrict__ cursor, int N) {
  __shared__ int wsum[16];
  int t = threadIdx.x, lane = t & 63, wv = t >> 6;
  int idx = blockIdx.x * 1024 + t;
  int v = (idx < N) ? counts[idx] : 0;
  int x = v;
#pragma unroll
  for (int off = 1; off < 64; off <<= 1) {
    int y = __shfl_up(x, off, 64);
    if (lane >= off) x += y;
  }
  if (lane == 63) wsum[wv] = x;
  __syncthreads();
  if (t == 0) {
    int run = 0;
#pragma unroll
    for (int k = 0; k < 16; ++k) { int s = wsum[k]; wsum[k] = run; run += s; }
  }
  __syncthreads();
  int excl = pscan[blockIdx.x] + wsum[wv] + x - v;
  if (idx < N) { offsets[idx] = excl; cursor[idx] = excl; }
}

__global__ __launch_bounds__(256) void k_scatter(const int* __restrict__ row,
    const int* __restrict__ col, int* __restrict__ cursor,
    int* __restrict__ csr, int E) {
  int e = blockIdx.x * 256 + threadIdx.x;
  if (e < E) {
    int i = row[e];
    int pos = atomicAdd(&cursor[i], 1);
    csr[pos] = col[e];
  }
}
// After k_scatter, cursor[i] == offsets[i] + counts[i]  (used as `ends`).

// x fp32 [N*64] -> bf16 [N*64], 4 elems/thread
__global__ __launch_bounds__(256) void k_cvt(const float4* __restrict__ x,
                                             uint2* __restrict__ xb, int n4) {
  int i = blockIdx.x * 256 + threadIdx.x;
  if (i >= n4) return;
  float4 v = x[i];
  uint2 p;
  p.x = packbf(v.x, v.y);
  p.y = packbf(v.z, v.w);
  xb[i] = p;
}

// hop1: one wave per node; 4 groups of 16 lanes each own one edge; each lane
// covers 4 features (8B uint2 of bf16). Writes packed xs1:
//   xs1a[n*64+f] = h0|h1<<16 (uint),  xs1b[n*64+f] = h2 (ushort)
// stored as uint4 / uint2 per (node, lane<16).
__global__ __launch_bounds__(256) void k_prop1(const uint2* __restrict__ xb2,
    const float* __restrict__ deg, const int* __restrict__ offsets,
    const int* __restrict__ ends, const int* __restrict__ csr,
    uint4* __restrict__ xs1a4, uint2* __restrict__ xs1b2, int N) {
  int w = (blockIdx.x * 256 + threadIdx.x) >> 6;
  int lane = threadIdx.x & 63;
  if (w >= N) return;
  int q = lane & 15;
  int g = lane >> 4;
  int beg = offsets[w];
  int end = ends[w];
  float s0[4] = {0.f, 0.f, 0.f, 0.f};
  float s1[4] = {0.f, 0.f, 0.f, 0.f};
  float s2[4] = {0.f, 0.f, 0.f, 0.f};
  int base = beg;
  for (; base + 8 <= end; base += 8) {           // 8 edges per iteration
    int j0 = csr[base + g];
    int j1 = csr[base + 4 + g];
    uint2 v0 = xb2[(size_t)j0 * 16 + q];
    uint2 v1 = xb2[(size_t)j1 * 16 + q];
    float d0 = deg[j0], d1 = deg[j1];
    float r0 = rsqrtf(d0), r1 = rsqrtf(d1);
    float p0 = d0 * r0, p1 = d1 * r1;
    float f00 = bflo(v0.x), f01 = bfhi(v0.x), f02 = bflo(v0.y), f03 = bfhi(v0.y);
    float f10 = bflo(v1.x), f11 = bfhi(v1.x), f12 = bflo(v1.y), f13 = bfhi(v1.y);
    s0[0] += f00 + f10; s0[1] += f01 + f11; s0[2] += f02 + f12; s0[3] += f03 + f13;
    s1[0] = fmaf(f00, r0, fmaf(f10, r1, s1[0]));
    s1[1] = fmaf(f01, r0, fmaf(f11, r1, s1[1]));
    s1[2] = fmaf(f02, r0, fmaf(f12, r1, s1[2]));
    s1[3] = fmaf(f03, r0, fmaf(f13, r1, s1[3]));
    s2[0] = fmaf(f00, p0, fmaf(f10, p1, s2[0]));
    s2[1] = fmaf(f01, p0, fmaf(f11, p1, s2[1]));
    s2[2] = fmaf(f02, p0, fmaf(f12, p1, s2[2]));
    s2[3] = fmaf(f03, p0, fmaf(f13, p1, s2[3]));
  }
  if (base < end) {                               // masked tail, up to 7 edges
    int e0 = base + g, e1 = base + 4 + g;
    bool a = e0 < end, b = e1 < end;
    int j0 = csr[a ? e0 : beg];
    int j1 = csr[b ? e1 : beg];
    uint2 v0 = xb2[(size_t)j0 * 16 + q];
    uint2 v1 = xb2[(size_t)j1 * 16 + q];
    float d0 = deg[j0], d1 = deg[j1];
    float m0 = a ? 1.f : 0.f, m1 = b ? 1.f : 0.f;
    float r0 = rsqrtf(d0) * m0, r1 = rsqrtf(d1) * m1;
    float p0 = d0 * r0, p1 = d1 * r1;
    float f00 = bflo(v0.x), f01 = bfhi(v0.x), f02 = bflo(v0.y), f03 = bfhi(v0.y);
    float f10 = bflo(v1.x), f11 = bfhi(v1.x), f12 = bflo(v1.y), f13 = bfhi(v1.y);
    s0[0] = fmaf(f00, m0, fmaf(f10, m1, s0[0]));
    s0[1] = fmaf(f01, m0, fmaf(f11, m1, s0[1]));
    s0[2] = fmaf(f02, m0, fmaf(f12, m1, s0[2]));
    s0[3] = fmaf(f03, m0, fmaf(f13, m1, s0[3]));
    s1[0] = fmaf(f00, r0, fmaf(f10, r1, s1[0]));
    s1[1] = fmaf(f01, r0, fmaf(f11, r1, s1[1]));
    s1[2] = fmaf(f02, r0, fmaf(f12, r1, s1[2]));
    s1[3] = fmaf(f03, r0, fmaf(f13, r1, s1[3]));
    s2[0] = fmaf(f00, p0, fmaf(f10, p1, s2[0]));
    s2[1] = fmaf(f01, p0, fmaf(f11, p1, s2[1]));
    s2[2] = fmaf(f02, p0, fmaf(f12, p1, s2[2]));
    s2[3] = fmaf(f03, p0, fmaf(f13, p1, s2[3]));
  }
#pragma unroll
  for (int k = 0; k < 4; ++k) {                   // cross-group reduce
    s0[k] += __shfl_xor(s0[k], 16, 64); s0[k] += __shfl_xor(s0[k], 32, 64);
    s1[k] += __shfl_xor(s1[k], 16, 64); s1[k] += __shfl_xor(s1[k], 32, 64);
    s2[k] += __shfl_xor(s2[k], 16, 64); s2[k] += __shfl_xor(s2[k], 32, 64);
  }
  if (g == 0) {
    float dr = 1.0f / deg[w];
    uint4 A;
    A.x = packbf(s0[0] * dr, s1[0] * dr);
    A.y = packbf(s0[1] * dr, s1[1] * dr);
    A.z = packbf(s0[2] * dr, s1[2] * dr);
    A.w = packbf(s0[3] * dr, s1[3] * dr);
    uint2 B;
    B.x = (unsigned)f2bf(s2[0] * dr) | ((unsigned)f2bf(s2[1] * dr) << 16);
    B.y = (unsigned)f2bf(s2[2] * dr) | ((unsigned)f2bf(s2[3] * dr) << 16);
    xs1a4[(size_t)w * 16 + q] = A;
    xs1b2[(size_t)w * 16 + q] = B;
  }
}

// hop2 + epilogue: same 4-edges-per-wave gather of packed xs1 (dwordx4 +
// dwordx2 per lane), cross-group reduce, redistribute to lane=d, then R1's
// full-line 9-float store.
__global__ __launch_bounds__(256) void k_prop2(const float* __restrict__ x,
    const float* __restrict__ deg, const int* __restrict__ offsets,
    const int* __restrict__ ends, const int* __restrict__ csr,
    const uint4* __restrict__ xs1a4, const uint2* __restrict__ xs1b2,
    const unsigned* __restrict__ xs1a, const unsigned short* __restrict__ xs1b,
    float* __restrict__ out, int N) {
  int w = (blockIdx.x * 256 + threadIdx.x) >> 6;
  int lane = threadIdx.x & 63;
  if (w >= N) return;
  int q = lane & 15;
  int g = lane >> 4;
  int beg = offsets[w];
  int end = ends[w];
  float a0[4] = {0.f, 0.f, 0.f, 0.f};
  float a1[4] = {0.f, 0.f, 0.f, 0.f};
  float a2[4] = {0.f, 0.f, 0.f, 0.f};
  int base = beg;
  for (; base + 8 <= end; base += 8) {
    int j0 = csr[base + g];
    int j1 = csr[base + 4 + g];
    uint4 pa0 = xs1a4[(size_t)j0 * 16 + q];
    uint4 pa1 = xs1a4[(size_t)j1 * 16 + q];
    uint2 pb0 = xs1b2[(size_t)j0 * 16 + q];
    uint2 pb1 = xs1b2[(size_t)j1 * 16 + q];
    a0[0] += bflo(pa0.x) + bflo(pa1.x);
    a0[1] += bflo(pa0.y) + bflo(pa1.y);
    a0[2] += bflo(pa0.z) + bflo(pa1.z);
    a0[3] += bflo(pa0.w) + bflo(pa1.w);
    a1[0] += bfhi(pa0.x) + bfhi(pa1.x);
    a1[1] += bfhi(pa0.y) + bfhi(pa1.y);
    a1[2] += bfhi(pa0.z) + bfhi(pa1.z);
    a1[3] += bfhi(pa0.w) + bfhi(pa1.w);
    a2[0] += bflo(pb0.x) + bflo(pb1.x);
    a2[1] += bfhi(pb0.x) + bfhi(pb1.x);
    a2[2] += bflo(pb0.y) + bflo(pb1.y);
    a2[3] += bfhi(pb0.y) + bfhi(pb1.y);
  }
  if (base < end) {
    int e0 = base + g, e1 = base + 4 + g;
    bool va = e0 < end, vb = e1 < end;
    int j0 = csr[va ? e0 : beg];
    int j1 = csr[vb ? e1 : beg];
    uint4 pa0 = xs1a4[(size_t)j0 * 16 + q];
    uint4 pa1 = xs1a4[(size_t)j1 * 16 + q];
    uint2 pb0 = xs1b2[(size_t)j0 * 16 + q];
    uint2 pb1 = xs1b2[(size_t)j1 * 16 + q];
    float m0 = va ? 1.f : 0.f, m1 = vb ? 1.f : 0.f;
    a0[0] = fmaf(bflo(pa0.x), m0, fmaf(bflo(pa1.x), m1, a0[0]));
    a0[1] = fmaf(bflo(pa0.y), m0, fmaf(bflo(pa1.y), m1, a0[1]));
    a0[2] = fmaf(bflo(pa0.z), m0, fmaf(bflo(pa1.z), m1, a0[2]));
    a0[3] = fmaf(bflo(pa0.w), m0, fmaf(bflo(pa1.w), m1, a0[3]));
    a1[0] = fmaf(bfhi(pa0.x), m0, fmaf(bfhi(pa1.x), m1, a1[0]));
    a1[1] = fmaf(bfhi(pa0.y), m0, fmaf(bfhi(pa1.y), m1, a1[1]));
    a1[2] = fmaf(bfhi(pa0.z), m0, fmaf(bfhi(pa1.z), m1, a1[2]));
    a1[3] = fmaf(bfhi(pa0.w), m0, fmaf(bfhi(pa1.w), m1, a1[3]));
    a2[0] = fmaf(bflo(pb0.x), m0, fmaf(bflo(pb1.x), m1, a2[0]));
    a2[1] = fmaf(bfhi(pb0.x), m0, fmaf(bfhi(pb1.x), m1, a2[1]));
    a2[2] = fmaf(bflo(pb0.y), m0, fmaf(bflo(pb1.y), m1, a2[2]));
    a2[3] = fmaf(bfhi(pb0.y), m0, fmaf(bfhi(pb1.y), m1, a2[3]));
  }
#pragma unroll
  for (int k = 0; k < 4; ++k) {
    a0[k] += __shfl_xor(a0[k], 16, 64); a0[k] += __shfl_xor(a0[k], 32, 64);
    a1[k] += __shfl_xor(a1[k], 16, 64); a1[k] += __shfl_xor(a1[k], 32, 64);
    a2[k] += __shfl_xor(a2[k], 16, 64); a2[k] += __shfl_xor(a2[k], 32, 64);
  }
  // redistribute: lane d needs sums for feature d (held at lane d>>2, slot d&3)
  int src = lane >> 2;
  int k = lane & 3;
  float A0 = sel4(__shfl(a0[0], src, 64), __shfl(a0[1], src, 64),
                  __shfl(a0[2], src, 64), __shfl(a0[3], src, 64), k);
  float A1 = sel4(__shfl(a1[0], src, 64), __shfl(a1[1], src, 64),
                  __shfl(a1[2], src, 64), __shfl(a1[3], src, 64), k);
  float A2 = sel4(__shfl(a2[0], src, 64), __shfl(a2[1], src, 64),
                  __shfl(a2[2], src, 64), __shfl(a2[3], src, 64), k);
  float degi = deg[w];
  float dr = 1.0f / degi;
  float ri = rsqrtf(degi);
  float qi = degi * ri;
  size_t b = (size_t)w * 64 + lane;
  float xv = x[b];
  unsigned pown = xs1a[b];
  float h0 = bflo(pown);
  float h1 = bfhi(pown);
  float h2 = bf2f(xs1b[b]);
  float o0 = xv, o1 = xv * ri, o2 = xv * qi;
  float* op = out + (size_t)w * 576 + (size_t)lane * 9;
  op[0] = o0; op[1] = o1; op[2] = o2;
  op[3] = h0; op[4] = h1; op[5] = h2;
  op[6] = A0 * dr - o0;
  op[7] = A1 * dr - o1;
  op[8] = A2 * dr - o2;
}

extern "C" void kernel_launch(void* const* d_in, const int* in_sizes, int n_in,
                              void* d_out, int out_size, void* d_ws, size_t ws_size,
                              hipStream_t stream) {
  const float* x   = (const float*)d_in[0];
  const float* deg = (const float*)d_in[1];
  const int*   row = (const int*)d_in[2];
  const int*   col = (const int*)d_in[3];
  float* out = (float*)d_out;

  int N = in_sizes[1];       // deg has N elements
  int E = in_sizes[2];       // row has E elements
  int NB = (N + 1023) / 1024;

  char* ws = (char*)d_ws;
  size_t off = 0;
  int* counts  = (int*)(ws + off); off = ws_align(off + (size_t)N * 4);
  int* offsets = (int*)(ws + off); off = ws_align(off + (size_t)N * 4);
  int* cursor  = (int*)(ws + off); off = ws_align(off + (size_t)N * 4);
  int* partial = (int*)(ws + off); off = ws_align(off + (size_t)NB * 4);
  int* pscan   = (int*)(ws + off); off = ws_align(off + (size_t)NB * 4);
  int* csr     = (int*)(ws + off); off = ws_align(off + (size_t)E * 4);
  unsigned short* xb = (unsigned short*)(ws + off); off = ws_align(off + (size_t)N * 64 * 2);
  unsigned* xs1a = (unsigned*)(ws + off); off = ws_align(off + (size_t)N * 64 * 4);
  unsigned short* xs1b = (unsigned short*)(ws + off); off = ws_align(off + (size_t)N * 64 * 2);
  // total ~59 MB; harness ws confirmed larger

  int n4 = N * 16;  // N*64/4 float4 groups
  k_cvt<<<(n4 + 255) / 256, 256, 0, stream>>>((const float4*)x, (uint2*)xb, n4);

  hipMemsetAsync(counts, 0, (size_t)N * 4, stream);
  k_hist<<<(E + 255) / 256, 256, 0, stream>>>(row, counts, E);
  k_blocksum<<<NB, 1024, 0, stream>>>(counts, partial, N);
  k_scanpartial<<<1, 128, 0, stream>>>(partial, pscan, NB);
  k_scanapply<<<NB, 1024, 0, stream>>>(counts, pscan, offsets, cursor, N);
  k_scatter<<<(E + 255) / 256, 256, 0, stream>>>(row, col, cursor, csr, E);

  int hopBlocks = (N + 3) / 4;   // 4 waves/block, 1 wave per node
  k_prop1<<<hopBlocks, 256, 0, stream>>>((const uint2*)xb, deg, offsets, cursor,
                                         csr, (uint4*)xs1a, (uint2*)xs1b, N);
  k_prop2<<<hopBlocks, 256, 0, stream>>>(x, deg, offsets, cursor, csr,
                                         (const uint4*)xs1a, (const uint2*)xs1b,
                                         xs1a, xs1b, out, N);
}

// Round 4
// 517.755 us; speedup vs baseline: 1.1683x; 1.1683x over previous
//
#include <hip/hip_runtime.h>

// NodeFeat: out[n,d,c] (c stride 1, d stride 9, n stride 576), c = hop*3 + part
//   hop0: x * {1, rsqrt(deg), sqrt(deg)}
//   hop1: (1/deg) * spmm(hop0)
//   hop2: (1/deg) * spmm(hop1) - hop0
// R5 changes (build-phase diet; revert of failed cooperative R4):
//   - k_hist + memset DELETED: per-node CSR slot count derived from deg
//     ((int)(deg+0.5)); zero-in-degree nodes over-allocate 1 unused slot
//     (csr sized E+N); `ends` = post-scatter cursor, so prop loops still see
//     the true in-degree. Saves a full 1.6M-atomic pass + 2 dispatches.
//   - k_cvt fused into k_scatter (independent bounds checks): 1 fewer launch;
//     cvt's streaming traffic hides under scatter's atomic latency.
//   - prop2: non-temporal stores for `out` (230MB stream no longer evicts the
//     38MB xs1 gather working set from L2) + nt load for own x row.
//   - prop1/prop2 arithmetic bit-identical to R2 (absmax must stay 0.125).

static inline size_t ws_align(size_t x) { return (x + 255) & ~(size_t)255; }

__device__ inline float bf2f(unsigned short s) {
  return __uint_as_float(((unsigned)s) << 16);
}
__device__ inline unsigned short f2bf(float f) {
  unsigned u = __float_as_uint(f);
  unsigned r = u + 0x7fff + ((u >> 16) & 1);   // round-to-nearest-even
  return (unsigned short)(r >> 16);
}
__device__ inline float bflo(unsigned p) { return __uint_as_float(p << 16); }
__device__ inline float bfhi(unsigned p) { return __uint_as_float(p & 0xffff0000u); }
__device__ inline unsigned packbf(float a, float b) {
  return (unsigned)f2bf(a) | ((unsigned)f2bf(b) << 16);
}
__device__ inline float sel4(float u0, float u1, float u2, float u3, int k) {
  float a = (k & 1) ? u1 : u0;
  float b = (k & 1) ? u3 : u2;
  return (k & 2) ? b : a;
}
__device__ inline void nts(float* p, float v) { __builtin_nontemporal_store(v, p); }

// per-1024-chunk sums of (int)deg -> partial
__global__ __launch_bounds__(1024) void k_blocksum(const float* __restrict__ deg,
                                                   int* __restrict__ partial, int N) {
  __shared__ int wsum[16];
  int t = threadIdx.x;
  int idx = blockIdx.x * 1024 + t;
  int v = (idx < N) ? (int)(deg[idx] + 0.5f) : 0;
  for (int off = 32; off; off >>= 1) v += __shfl_down(v, off, 64);
  if ((t & 63) == 0) wsum[t >> 6] = v;
  __syncthreads();
  if (t == 0) {
    int s = 0;
#pragma unroll
    for (int k = 0; k < 16; ++k) s += wsum[k];
    partial[blockIdx.x] = s;
  }
}

__global__ void k_scanpartial(const int* __restrict__ partial,
                              int* __restrict__ pscan, int NB) {
  __shared__ int buf[1024];
  int t = threadIdx.x;
  for (int k = t; k < NB; k += blockDim.x) buf[k] = partial[k];
  __syncthreads();
  if (t == 0) {
    int run = 0;
    for (int k = 0; k < NB; ++k) { int v = buf[k]; buf[k] = run; run += v; }
  }
  __syncthreads();
  for (int k = t; k < NB; k += blockDim.x) pscan[k] = buf[k];
}

__global__ __launch_bounds__(1024) void k_scanapply(const float* __restrict__ deg,
    const int* __restrict__ pscan, int* __restrict__ offsets,
    int* __restrict__ cursor, int N) {
  __shared__ int wsum[16];
  int t = threadIdx.x, lane = t & 63, wv = t >> 6;
  int idx = blockIdx.x * 1024 + t;
  int v = (idx < N) ? (int)(deg[idx] + 0.5f) : 0;
  int x = v;
#pragma unroll
  for (int off = 1; off < 64; off <<= 1) {
    int y = __shfl_up(x, off, 64);
    if (lane >= off) x += y;
  }
  if (lane == 63) wsum[wv] = x;
  __syncthreads();
  if (t == 0) {
    int run = 0;
#pragma unroll
    for (int k = 0; k < 16; ++k) { int s = wsum[k]; wsum[k] = run; run += s; }
  }
  __syncthreads();
  int excl = pscan[blockIdx.x] + wsum[wv] + x - v;
  if (idx < N) { offsets[idx] = excl; cursor[idx] = excl; }
}

// fused: cvt (x fp32 -> bf16 xb, i < n4) + scatter (e < E)
__global__ __launch_bounds__(256) void k_scatter_cvt(const float4* __restrict__ x4,
    uint2* __restrict__ xb2, const int* __restrict__ row,
    const int* __restrict__ col, int* __restrict__ cursor,
    int* __restrict__ csr, int E, int n4) {
  int i = blockIdx.x * 256 + threadIdx.x;
  if (i < n4) {
    float4 v = x4[i];
    uint2 p;
    p.x = packbf(v.x, v.y);
    p.y = packbf(v.z, v.w);
    xb2[i] = p;
  }
  if (i < E) {
    int r = row[i];
    int pos = atomicAdd(&cursor[r], 1);
    csr[pos] = col[i];
  }
}
// After k_scatter_cvt, cursor[i] == offsets[i] + true_count[i]  (used as `ends`).

// hop1: one wave per node; 4 groups of 16 lanes each own one edge; each lane
// covers 4 features. Writes packed xs1 (uint4: h0|h1, uint2: h2).
__global__ __launch_bounds__(256) void k_prop1(const uint2* __restrict__ xb2,
    const float* __restrict__ deg, const int* __restrict__ offsets,
    const int* __restrict__ ends, const int* __restrict__ csr,
    uint4* __restrict__ xs1a4, uint2* __restrict__ xs1b2, int N) {
  int w = (blockIdx.x * 256 + threadIdx.x) >> 6;
  int lane = threadIdx.x & 63;
  if (w >= N) return;
  int q = lane & 15;
  int g = lane >> 4;
  int beg = offsets[w];
  int end = ends[w];
  float s0[4] = {0.f, 0.f, 0.f, 0.f};
  float s1[4] = {0.f, 0.f, 0.f, 0.f};
  float s2[4] = {0.f, 0.f, 0.f, 0.f};
  int base = beg;
  for (; base + 8 <= end; base += 8) {           // 8 edges per iteration
    int j0 = csr[base + g];
    int j1 = csr[base + 4 + g];
    uint2 v0 = xb2[(size_t)j0 * 16 + q];
    uint2 v1 = xb2[(size_t)j1 * 16 + q];
    float d0 = deg[j0], d1 = deg[j1];
    float r0 = rsqrtf(d0), r1 = rsqrtf(d1);
    float p0 = d0 * r0, p1 = d1 * r1;
    float f00 = bflo(v0.x), f01 = bfhi(v0.x), f02 = bflo(v0.y), f03 = bfhi(v0.y);
    float f10 = bflo(v1.x), f11 = bfhi(v1.x), f12 = bflo(v1.y), f13 = bfhi(v1.y);
    s0[0] += f00 + f10; s0[1] += f01 + f11; s0[2] += f02 + f12; s0[3] += f03 + f13;
    s1[0] = fmaf(f00, r0, fmaf(f10, r1, s1[0]));
    s1[1] = fmaf(f01, r0, fmaf(f11, r1, s1[1]));
    s1[2] = fmaf(f02, r0, fmaf(f12, r1, s1[2]));
    s1[3] = fmaf(f03, r0, fmaf(f13, r1, s1[3]));
    s2[0] = fmaf(f00, p0, fmaf(f10, p1, s2[0]));
    s2[1] = fmaf(f01, p0, fmaf(f11, p1, s2[1]));
    s2[2] = fmaf(f02, p0, fmaf(f12, p1, s2[2]));
    s2[3] = fmaf(f03, p0, fmaf(f13, p1, s2[3]));
  }
  if (base < end) {                               // masked tail, up to 7 edges
    int e0 = base + g, e1 = base + 4 + g;
    bool a = e0 < end, b = e1 < end;
    int j0 = csr[a ? e0 : beg];
    int j1 = csr[b ? e1 : beg];
    uint2 v0 = xb2[(size_t)j0 * 16 + q];
    uint2 v1 = xb2[(size_t)j1 * 16 + q];
    float d0 = deg[j0], d1 = deg[j1];
    float m0 = a ? 1.f : 0.f, m1 = b ? 1.f : 0.f;
    float r0 = rsqrtf(d0) * m0, r1 = rsqrtf(d1) * m1;
    float p0 = d0 * r0, p1 = d1 * r1;
    float f00 = bflo(v0.x), f01 = bfhi(v0.x), f02 = bflo(v0.y), f03 = bfhi(v0.y);
    float f10 = bflo(v1.x), f11 = bfhi(v1.x), f12 = bflo(v1.y), f13 = bfhi(v1.y);
    s0[0] = fmaf(f00, m0, fmaf(f10, m1, s0[0]));
    s0[1] = fmaf(f01, m0, fmaf(f11, m1, s0[1]));
    s0[2] = fmaf(f02, m0, fmaf(f12, m1, s0[2]));
    s0[3] = fmaf(f03, m0, fmaf(f13, m1, s0[3]));
    s1[0] = fmaf(f00, r0, fmaf(f10, r1, s1[0]));
    s1[1] = fmaf(f01, r0, fmaf(f11, r1, s1[1]));
    s1[2] = fmaf(f02, r0, fmaf(f12, r1, s1[2]));
    s1[3] = fmaf(f03, r0, fmaf(f13, r1, s1[3]));
    s2[0] = fmaf(f00, p0, fmaf(f10, p1, s2[0]));
    s2[1] = fmaf(f01, p0, fmaf(f11, p1, s2[1]));
    s2[2] = fmaf(f02, p0, fmaf(f12, p1, s2[2]));
    s2[3] = fmaf(f03, p0, fmaf(f13, p1, s2[3]));
  }
#pragma unroll
  for (int k = 0; k < 4; ++k) {                   // cross-group reduce
    s0[k] += __shfl_xor(s0[k], 16, 64); s0[k] += __shfl_xor(s0[k], 32, 64);
    s1[k] += __shfl_xor(s1[k], 16, 64); s1[k] += __shfl_xor(s1[k], 32, 64);
    s2[k] += __shfl_xor(s2[k], 16, 64); s2[k] += __shfl_xor(s2[k], 32, 64);
  }
  if (g == 0) {
    float dr = 1.0f / deg[w];
    uint4 A;
    A.x = packbf(s0[0] * dr, s1[0] * dr);
    A.y = packbf(s0[1] * dr, s1[1] * dr);
    A.z = packbf(s0[2] * dr, s1[2] * dr);
    A.w = packbf(s0[3] * dr, s1[3] * dr);
    uint2 B;
    B.x = (unsigned)f2bf(s2[0] * dr) | ((unsigned)f2bf(s2[1] * dr) << 16);
    B.y = (unsigned)f2bf(s2[2] * dr) | ((unsigned)f2bf(s2[3] * dr) << 16);
    xs1a4[(size_t)w * 16 + q] = A;
    xs1b2[(size_t)w * 16 + q] = B;
  }
}

// hop2 + epilogue: 4-edges-per-wave gather of packed xs1, cross-group reduce,
// redistribute to lane=d, nt-store full 9-float line.
__global__ __launch_bounds__(256) void k_prop2(const float* __restrict__ x,
    const float* __restrict__ deg, const int* __restrict__ offsets,
    const int* __restrict__ ends, const int* __restrict__ csr,
    const uint4* __restrict__ xs1a4, const uint2* __restrict__ xs1b2,
    const unsigned* __restrict__ xs1a, const unsigned short* __restrict__ xs1b,
    float* __restrict__ out, int N) {
  int w = (blockIdx.x * 256 + threadIdx.x) >> 6;
  int lane = threadIdx.x & 63;
  if (w >= N) return;
  int q = lane & 15;
  int g = lane >> 4;
  int beg = offsets[w];
  int end = ends[w];
  float a0[4] = {0.f, 0.f, 0.f, 0.f};
  float a1[4] = {0.f, 0.f, 0.f, 0.f};
  float a2[4] = {0.f, 0.f, 0.f, 0.f};
  int base = beg;
  for (; base + 8 <= end; base += 8) {
    int j0 = csr[base + g];
    int j1 = csr[base + 4 + g];
    uint4 pa0 = xs1a4[(size_t)j0 * 16 + q];
    uint4 pa1 = xs1a4[(size_t)j1 * 16 + q];
    uint2 pb0 = xs1b2[(size_t)j0 * 16 + q];
    uint2 pb1 = xs1b2[(size_t)j1 * 16 + q];
    a0[0] += bflo(pa0.x) + bflo(pa1.x);
    a0[1] += bflo(pa0.y) + bflo(pa1.y);
    a0[2] += bflo(pa0.z) + bflo(pa1.z);
    a0[3] += bflo(pa0.w) + bflo(pa1.w);
    a1[0] += bfhi(pa0.x) + bfhi(pa1.x);
    a1[1] += bfhi(pa0.y) + bfhi(pa1.y);
    a1[2] += bfhi(pa0.z) + bfhi(pa1.z);
    a1[3] += bfhi(pa0.w) + bfhi(pa1.w);
    a2[0] += bflo(pb0.x) + bflo(pb1.x);
    a2[1] += bfhi(pb0.x) + bfhi(pb1.x);
    a2[2] += bflo(pb0.y) + bflo(pb1.y);
    a2[3] += bfhi(pb0.y) + bfhi(pb1.y);
  }
  if (base < end) {
    int e0 = base + g, e1 = base + 4 + g;
    bool va = e0 < end, vb = e1 < end;
    int j0 = csr[va ? e0 : beg];
    int j1 = csr[vb ? e1 : beg];
    uint4 pa0 = xs1a4[(size_t)j0 * 16 + q];
    uint4 pa1 = xs1a4[(size_t)j1 * 16 + q];
    uint2 pb0 = xs1b2[(size_t)j0 * 16 + q];
    uint2 pb1 = xs1b2[(size_t)j1 * 16 + q];
    float m0 = va ? 1.f : 0.f, m1 = vb ? 1.f : 0.f;
    a0[0] = fmaf(bflo(pa0.x), m0, fmaf(bflo(pa1.x), m1, a0[0]));
    a0[1] = fmaf(bflo(pa0.y), m0, fmaf(bflo(pa1.y), m1, a0[1]));
    a0[2] = fmaf(bflo(pa0.z), m0, fmaf(bflo(pa1.z), m1, a0[2]));
    a0[3] = fmaf(bflo(pa0.w), m0, fmaf(bflo(pa1.w), m1, a0[3]));
    a1[0] = fmaf(bfhi(pa0.x), m0, fmaf(bfhi(pa1.x), m1, a1[0]));
    a1[1] = fmaf(bfhi(pa0.y), m0, fmaf(bfhi(pa1.y), m1, a1[1]));
    a1[2] = fmaf(bfhi(pa0.z), m0, fmaf(bfhi(pa1.z), m1, a1[2]));
    a1[3] = fmaf(bfhi(pa0.w), m0, fmaf(bfhi(pa1.w), m1, a1[3]));
    a2[0] = fmaf(bflo(pb0.x), m0, fmaf(bflo(pb1.x), m1, a2[0]));
    a2[1] = fmaf(bfhi(pb0.x), m0, fmaf(bfhi(pb1.x), m1, a2[1]));
    a2[2] = fmaf(bflo(pb0.y), m0, fmaf(bflo(pb1.y), m1, a2[2]));
    a2[3] = fmaf(bfhi(pb0.y), m0, fmaf(bfhi(pb1.y), m1, a2[3]));
  }
#pragma unroll
  for (int k = 0; k < 4; ++k) {
    a0[k] += __shfl_xor(a0[k], 16, 64); a0[k] += __shfl_xor(a0[k], 32, 64);
    a1[k] += __shfl_xor(a1[k], 16, 64); a1[k] += __shfl_xor(a1[k], 32, 64);
    a2[k] += __shfl_xor(a2[k], 16, 64); a2[k] += __shfl_xor(a2[k], 32, 64);
  }
  // redistribute: lane d needs sums for feature d (held at lane d>>2, slot d&3)
  int src = lane >> 2;
  int k = lane & 3;
  float A0 = sel4(__shfl(a0[0], src, 64), __shfl(a0[1], src, 64),
                  __shfl(a0[2], src, 64), __shfl(a0[3], src, 64), k);
  float A1 = sel4(__shfl(a1[0], src, 64), __shfl(a1[1], src, 64),
                  __shfl(a1[2], src, 64), __shfl(a1[3], src, 64), k);
  float A2 = sel4(__shfl(a2[0], src, 64), __shfl(a2[1], src, 64),
                  __shfl(a2[2], src, 64), __shfl(a2[3], src, 64), k);
  float degi = deg[w];
  float dr = 1.0f / degi;
  float ri = rsqrtf(degi);
  float qi = degi * ri;
  size_t b = (size_t)w * 64 + lane;
  float xv = __builtin_nontemporal_load(&x[b]);
  unsigned pown = xs1a[b];
  float h0 = bflo(pown);
  float h1 = bfhi(pown);
  float h2 = bf2f(xs1b[b]);
  float o0 = xv, o1 = xv * ri, o2 = xv * qi;
  float* op = out + (size_t)w * 576 + (size_t)lane * 9;
  nts(op + 0, o0); nts(op + 1, o1); nts(op + 2, o2);
  nts(op + 3, h0); nts(op + 4, h1); nts(op + 5, h2);
  nts(op + 6, a0[0] * 0.f + A0 * dr - o0);  // keep expression simple; see below
  nts(op + 7, A1 * dr - o1);
  nts(op + 8, A2 * dr - o2);
}

extern "C" void kernel_launch(void* const* d_in, const int* in_sizes, int n_in,
                              void* d_out, int out_size, void* d_ws, size_t ws_size,
                              hipStream_t stream) {
  const float* x   = (const float*)d_in[0];
  const float* deg = (const float*)d_in[1];
  const int*   row = (const int*)d_in[2];
  const int*   col = (const int*)d_in[3];
  float* out = (float*)d_out;

  int N = in_sizes[1];       // deg has N elements
  int E = in_sizes[2];       // row has E elements
  int NB = (N + 1023) / 1024;

  char* ws = (char*)d_ws;
  size_t off = 0;
  int* offsets = (int*)(ws + off); off = ws_align(off + (size_t)N * 4);
  int* cursor  = (int*)(ws + off); off = ws_align(off + (size_t)N * 4);
  int* partial = (int*)(ws + off); off = ws_align(off + (size_t)NB * 4);
  int* pscan   = (int*)(ws + off); off = ws_align(off + (size_t)NB * 4);
  int* csr     = (int*)(ws + off); off = ws_align(off + ((size_t)E + N) * 4);
  unsigned short* xb = (unsigned short*)(ws + off); off = ws_align(off + (size_t)N * 64 * 2);
  unsigned* xs1a = (unsigned*)(ws + off); off = ws_align(off + (size_t)N * 64 * 4);
  unsigned short* xs1b = (unsigned short*)(ws + off); off = ws_align(off + (size_t)N * 64 * 2);
  // total ~59 MB; harness ws confirmed larger

  k_blocksum<<<NB, 1024, 0, stream>>>(deg, partial, N);
  k_scanpartial<<<1, 128, 0, stream>>>(partial, pscan, NB);
  k_scanapply<<<NB, 1024, 0, stream>>>(deg, pscan, offsets, cursor, N);

  int n4 = N * 16;  // N*64/4 float4 groups
  int mx = (E > n4) ? E : n4;
  k_scatter_cvt<<<(mx + 255) / 256, 256, 0, stream>>>((const float4*)x,
      (uint2*)xb, row, col, cursor, csr, E, n4);

  int hopBlocks = (N + 3) / 4;   // 4 waves/block, 1 wave per node
  k_prop1<<<hopBlocks, 256, 0, stream>>>((const uint2*)xb, deg, offsets, cursor,
                                         csr, (uint4*)xs1a, (uint2*)xs1b, N);
  k_prop2<<<hopBlocks, 256, 0, stream>>>(x, deg, offsets, cursor, csr,
                                         (const uint4*)xs1a, (const uint2*)xs1b,
                                         xs1a, xs1b, out, N);
}

// Round 6
// 484.939 us; speedup vs baseline: 1.2474x; 1.0677x over previous
//
#include <hip/hip_runtime.h>

// NodeFeat: out[n,d,c] (c stride 1, d stride 9, n stride 576), c = hop*3 + part
//   hop0: x * {1, rsqrt(deg), sqrt(deg)}
//   hop1: (1/deg) * spmm(hop0)
//   hop2: (1/deg) * spmm(hop1) - hop0
// R6 = R5 with compile fix: __builtin_nontemporal_store needs a clang native
// vector type, not HIP_vector_type<float,4>. Use ext_vector_type(4).
// R5 theory: R4's 9 scalar nt-stores/lane wrote partial 64B lines (stride
// 36B) -> HBM RMW (WRITE 354MB vs 230 ideal, FETCH +239MB). Now: stage the
// wave's 576 contiguous output floats in LDS (lane*9+k, gcd(9,32)=1 -> 2
// lanes/bank, free), then 144 aligned 16B nt-stores (full lines; nt keeps the
// 230MB stream from evicting the 38MB xs1 gather set).

static inline size_t ws_align(size_t x) { return (x + 255) & ~(size_t)255; }

typedef float vfloat4 __attribute__((ext_vector_type(4)));

__device__ inline float bf2f(unsigned short s) {
  return __uint_as_float(((unsigned)s) << 16);
}
__device__ inline unsigned short f2bf(float f) {
  unsigned u = __float_as_uint(f);
  unsigned r = u + 0x7fff + ((u >> 16) & 1);   // round-to-nearest-even
  return (unsigned short)(r >> 16);
}
__device__ inline float bflo(unsigned p) { return __uint_as_float(p << 16); }
__device__ inline float bfhi(unsigned p) { return __uint_as_float(p & 0xffff0000u); }
__device__ inline unsigned packbf(float a, float b) {
  return (unsigned)f2bf(a) | ((unsigned)f2bf(b) << 16);
}
__device__ inline float sel4(float u0, float u1, float u2, float u3, int k) {
  float a = (k & 1) ? u1 : u0;
  float b = (k & 1) ? u3 : u2;
  return (k & 2) ? b : a;
}

// per-1024-chunk sums of (int)deg -> partial
__global__ __launch_bounds__(1024) void k_blocksum(const float* __restrict__ deg,
                                                   int* __restrict__ partial, int N) {
  __shared__ int wsum[16];
  int t = threadIdx.x;
  int idx = blockIdx.x * 1024 + t;
  int v = (idx < N) ? (int)(deg[idx] + 0.5f) : 0;
  for (int off = 32; off; off >>= 1) v += __shfl_down(v, off, 64);
  if ((t & 63) == 0) wsum[t >> 6] = v;
  __syncthreads();
  if (t == 0) {
    int s = 0;
#pragma unroll
    for (int k = 0; k < 16; ++k) s += wsum[k];
    partial[blockIdx.x] = s;
  }
}

__global__ void k_scanpartial(const int* __restrict__ partial,
                              int* __restrict__ pscan, int NB) {
  __shared__ int buf[1024];
  int t = threadIdx.x;
  for (int k = t; k < NB; k += blockDim.x) buf[k] = partial[k];
  __syncthreads();
  if (t == 0) {
    int run = 0;
    for (int k = 0; k < NB; ++k) { int v = buf[k]; buf[k] = run; run += v; }
  }
  __syncthreads();
  for (int k = t; k < NB; k += blockDim.x) pscan[k] = buf[k];
}

__global__ __launch_bounds__(1024) void k_scanapply(const float* __restrict__ deg,
    const int* __restrict__ pscan, int* __restrict__ offsets,
    int* __restrict__ cursor, int N) {
  __shared__ int wsum[16];
  int t = threadIdx.x, lane = t & 63, wv = t >> 6;
  int idx = blockIdx.x * 1024 + t;
  int v = (idx < N) ? (int)(deg[idx] + 0.5f) : 0;
  int x = v;
#pragma unroll
  for (int off = 1; off < 64; off <<= 1) {
    int y = __shfl_up(x, off, 64);
    if (lane >= off) x += y;
  }
  if (lane == 63) wsum[wv] = x;
  __syncthreads();
  if (t == 0) {
    int run = 0;
#pragma unroll
    for (int k = 0; k < 16; ++k) { int s = wsum[k]; wsum[k] = run; run += s; }
  }
  __syncthreads();
  int excl = pscan[blockIdx.x] + wsum[wv] + x - v;
  if (idx < N) { offsets[idx] = excl; cursor[idx] = excl; }
}

// fused: cvt (x fp32 -> bf16 xb, i < n4) + scatter (e < E)
__global__ __launch_bounds__(256) void k_scatter_cvt(const float4* __restrict__ x4,
    uint2* __restrict__ xb2, const int* __restrict__ row,
    const int* __restrict__ col, int* __restrict__ cursor,
    int* __restrict__ csr, int E, int n4) {
  int i = blockIdx.x * 256 + threadIdx.x;
  if (i < n4) {
    float4 v = x4[i];
    uint2 p;
    p.x = packbf(v.x, v.y);
    p.y = packbf(v.z, v.w);
    xb2[i] = p;
  }
  if (i < E) {
    int r = row[i];
    int pos = atomicAdd(&cursor[r], 1);
    csr[pos] = col[i];
  }
}
// After k_scatter_cvt, cursor[i] == offsets[i] + true_count[i]  (used as `ends`).

// hop1: one wave per node; 4 groups of 16 lanes each own one edge; each lane
// covers 4 features. Writes packed xs1 (uint4: h0|h1, uint2: h2).
__global__ __launch_bounds__(256) void k_prop1(const uint2* __restrict__ xb2,
    const float* __restrict__ deg, const int* __restrict__ offsets,
    const int* __restrict__ ends, const int* __restrict__ csr,
    uint4* __restrict__ xs1a4, uint2* __restrict__ xs1b2, int N) {
  int w = (blockIdx.x * 256 + threadIdx.x) >> 6;
  int lane = threadIdx.x & 63;
  if (w >= N) return;
  int q = lane & 15;
  int g = lane >> 4;
  int beg = offsets[w];
  int end = ends[w];
  float s0[4] = {0.f, 0.f, 0.f, 0.f};
  float s1[4] = {0.f, 0.f, 0.f, 0.f};
  float s2[4] = {0.f, 0.f, 0.f, 0.f};
  int base = beg;
  for (; base + 8 <= end; base += 8) {           // 8 edges per iteration
    int j0 = csr[base + g];
    int j1 = csr[base + 4 + g];
    uint2 v0 = xb2[(size_t)j0 * 16 + q];
    uint2 v1 = xb2[(size_t)j1 * 16 + q];
    float d0 = deg[j0], d1 = deg[j1];
    float r0 = rsqrtf(d0), r1 = rsqrtf(d1);
    float p0 = d0 * r0, p1 = d1 * r1;
    float f00 = bflo(v0.x), f01 = bfhi(v0.x), f02 = bflo(v0.y), f03 = bfhi(v0.y);
    float f10 = bflo(v1.x), f11 = bfhi(v1.x), f12 = bflo(v1.y), f13 = bfhi(v1.y);
    s0[0] += f00 + f10; s0[1] += f01 + f11; s0[2] += f02 + f12; s0[3] += f03 + f13;
    s1[0] = fmaf(f00, r0, fmaf(f10, r1, s1[0]));
    s1[1] = fmaf(f01, r0, fmaf(f11, r1, s1[1]));
    s1[2] = fmaf(f02, r0, fmaf(f12, r1, s1[2]));
    s1[3] = fmaf(f03, r0, fmaf(f13, r1, s1[3]));
    s2[0] = fmaf(f00, p0, fmaf(f10, p1, s2[0]));
    s2[1] = fmaf(f01, p0, fmaf(f11, p1, s2[1]));
    s2[2] = fmaf(f02, p0, fmaf(f12, p1, s2[2]));
    s2[3] = fmaf(f03, p0, fmaf(f13, p1, s2[3]));
  }
  if (base < end) {                               // masked tail, up to 7 edges
    int e0 = base + g, e1 = base + 4 + g;
    bool a = e0 < end, b = e1 < end;
    int j0 = csr[a ? e0 : beg];
    int j1 = csr[b ? e1 : beg];
    uint2 v0 = xb2[(size_t)j0 * 16 + q];
    uint2 v1 = xb2[(size_t)j1 * 16 + q];
    float d0 = deg[j0], d1 = deg[j1];
    float m0 = a ? 1.f : 0.f, m1 = b ? 1.f : 0.f;
    float r0 = rsqrtf(d0) * m0, r1 = rsqrtf(d1) * m1;
    float p0 = d0 * r0, p1 = d1 * r1;
    float f00 = bflo(v0.x), f01 = bfhi(v0.x), f02 = bflo(v0.y), f03 = bfhi(v0.y);
    float f10 = bflo(v1.x), f11 = bfhi(v1.x), f12 = bflo(v1.y), f13 = bfhi(v1.y);
    s0[0] = fmaf(f00, m0, fmaf(f10, m1, s0[0]));
    s0[1] = fmaf(f01, m0, fmaf(f11, m1, s0[1]));
    s0[2] = fmaf(f02, m0, fmaf(f12, m1, s0[2]));
    s0[3] = fmaf(f03, m0, fmaf(f13, m1, s0[3]));
    s1[0] = fmaf(f00, r0, fmaf(f10, r1, s1[0]));
    s1[1] = fmaf(f01, r0, fmaf(f11, r1, s1[1]));
    s1[2] = fmaf(f02, r0, fmaf(f12, r1, s1[2]));
    s1[3] = fmaf(f03, r0, fmaf(f13, r1, s1[3]));
    s2[0] = fmaf(f00, p0, fmaf(f10, p1, s2[0]));
    s2[1] = fmaf(f01, p0, fmaf(f11, p1, s2[1]));
    s2[2] = fmaf(f02, p0, fmaf(f12, p1, s2[2]));
    s2[3] = fmaf(f03, p0, fmaf(f13, p1, s2[3]));
  }
#pragma unroll
  for (int k = 0; k < 4; ++k) {                   // cross-group reduce
    s0[k] += __shfl_xor(s0[k], 16, 64); s0[k] += __shfl_xor(s0[k], 32, 64);
    s1[k] += __shfl_xor(s1[k], 16, 64); s1[k] += __shfl_xor(s1[k], 32, 64);
    s2[k] += __shfl_xor(s2[k], 16, 64); s2[k] += __shfl_xor(s2[k], 32, 64);
  }
  if (g == 0) {
    float dr = 1.0f / deg[w];
    uint4 A;
    A.x = packbf(s0[0] * dr, s1[0] * dr);
    A.y = packbf(s0[1] * dr, s1[1] * dr);
    A.z = packbf(s0[2] * dr, s1[2] * dr);
    A.w = packbf(s0[3] * dr, s1[3] * dr);
    uint2 B;
    B.x = (unsigned)f2bf(s2[0] * dr) | ((unsigned)f2bf(s2[1] * dr) << 16);
    B.y = (unsigned)f2bf(s2[2] * dr) | ((unsigned)f2bf(s2[3] * dr) << 16);
    xs1a4[(size_t)w * 16 + q] = A;
    xs1b2[(size_t)w * 16 + q] = B;
  }
}

// hop2 + epilogue: 4-edges-per-wave gather of packed xs1, cross-group reduce,
// redistribute to lane=d, LDS-stage 576 floats, 144 aligned 16B nt-stores.
__global__ __launch_bounds__(256) void k_prop2(const float* __restrict__ x,
    const float* __restrict__ deg, const int* __restrict__ offsets,
    const int* __restrict__ ends, const int* __restrict__ csr,
    const uint4* __restrict__ xs1a4, const uint2* __restrict__ xs1b2,
    const unsigned* __restrict__ xs1a, const unsigned short* __restrict__ xs1b,
    float* __restrict__ out, int N) {
  __shared__ __align__(16) float obuf[4][576];
  int w = (blockIdx.x * 256 + threadIdx.x) >> 6;
  int lane = threadIdx.x & 63;
  if (w >= N) return;
  int q = lane & 15;
  int g = lane >> 4;
  int beg = offsets[w];
  int end = ends[w];
  float a0[4] = {0.f, 0.f, 0.f, 0.f};
  float a1[4] = {0.f, 0.f, 0.f, 0.f};
  float a2[4] = {0.f, 0.f, 0.f, 0.f};
  int base = beg;
  for (; base + 8 <= end; base += 8) {
    int j0 = csr[base + g];
    int j1 = csr[base + 4 + g];
    uint4 pa0 = xs1a4[(size_t)j0 * 16 + q];
    uint4 pa1 = xs1a4[(size_t)j1 * 16 + q];
    uint2 pb0 = xs1b2[(size_t)j0 * 16 + q];
    uint2 pb1 = xs1b2[(size_t)j1 * 16 + q];
    a0[0] += bflo(pa0.x) + bflo(pa1.x);
    a0[1] += bflo(pa0.y) + bflo(pa1.y);
    a0[2] += bflo(pa0.z) + bflo(pa1.z);
    a0[3] += bflo(pa0.w) + bflo(pa1.w);
    a1[0] += bfhi(pa0.x) + bfhi(pa1.x);
    a1[1] += bfhi(pa0.y) + bfhi(pa1.y);
    a1[2] += bfhi(pa0.z) + bfhi(pa1.z);
    a1[3] += bfhi(pa0.w) + bfhi(pa1.w);
    a2[0] += bflo(pb0.x) + bflo(pb1.x);
    a2[1] += bfhi(pb0.x) + bfhi(pb1.x);
    a2[2] += bflo(pb0.y) + bflo(pb1.y);
    a2[3] += bfhi(pb0.y) + bfhi(pb1.y);
  }
  if (base < end) {
    int e0 = base + g, e1 = base + 4 + g;
    bool va = e0 < end, vb = e1 < end;
    int j0 = csr[va ? e0 : beg];
    int j1 = csr[vb ? e1 : beg];
    uint4 pa0 = xs1a4[(size_t)j0 * 16 + q];
    uint4 pa1 = xs1a4[(size_t)j1 * 16 + q];
    uint2 pb0 = xs1b2[(size_t)j0 * 16 + q];
    uint2 pb1 = xs1b2[(size_t)j1 * 16 + q];
    float m0 = va ? 1.f : 0.f, m1 = vb ? 1.f : 0.f;
    a0[0] = fmaf(bflo(pa0.x), m0, fmaf(bflo(pa1.x), m1, a0[0]));
    a0[1] = fmaf(bflo(pa0.y), m0, fmaf(bflo(pa1.y), m1, a0[1]));
    a0[2] = fmaf(bflo(pa0.z), m0, fmaf(bflo(pa1.z), m1, a0[2]));
    a0[3] = fmaf(bflo(pa0.w), m0, fmaf(bflo(pa1.w), m1, a0[3]));
    a1[0] = fmaf(bfhi(pa0.x), m0, fmaf(bfhi(pa1.x), m1, a1[0]));
    a1[1] = fmaf(bfhi(pa0.y), m0, fmaf(bfhi(pa1.y), m1, a1[1]));
    a1[2] = fmaf(bfhi(pa0.z), m0, fmaf(bfhi(pa1.z), m1, a1[2]));
    a1[3] = fmaf(bfhi(pa0.w), m0, fmaf(bfhi(pa1.w), m1, a1[3]));
    a2[0] = fmaf(bflo(pb0.x), m0, fmaf(bflo(pb1.x), m1, a2[0]));
    a2[1] = fmaf(bfhi(pb0.x), m0, fmaf(bfhi(pb1.x), m1, a2[1]));
    a2[2] = fmaf(bflo(pb0.y), m0, fmaf(bflo(pb1.y), m1, a2[2]));
    a2[3] = fmaf(bfhi(pb0.y), m0, fmaf(bfhi(pb1.y), m1, a2[3]));
  }
#pragma unroll
  for (int k = 0; k < 4; ++k) {
    a0[k] += __shfl_xor(a0[k], 16, 64); a0[k] += __shfl_xor(a0[k], 32, 64);
    a1[k] += __shfl_xor(a1[k], 16, 64); a1[k] += __shfl_xor(a1[k], 32, 64);
    a2[k] += __shfl_xor(a2[k], 16, 64); a2[k] += __shfl_xor(a2[k], 32, 64);
  }
  // redistribute: lane d needs sums for feature d (held at lane d>>2, slot d&3)
  int src = lane >> 2;
  int k = lane & 3;
  float A0 = sel4(__shfl(a0[0], src, 64), __shfl(a0[1], src, 64),
                  __shfl(a0[2], src, 64), __shfl(a0[3], src, 64), k);
  float A1 = sel4(__shfl(a1[0], src, 64), __shfl(a1[1], src, 64),
                  __shfl(a1[2], src, 64), __shfl(a1[3], src, 64), k);
  float A2 = sel4(__shfl(a2[0], src, 64), __shfl(a2[1], src, 64),
                  __shfl(a2[2], src, 64), __shfl(a2[3], src, 64), k);
  float degi = deg[w];
  float dr = 1.0f / degi;
  float ri = rsqrtf(degi);
  float qi = degi * ri;
  size_t b = (size_t)w * 64 + lane;
  float xv = __builtin_nontemporal_load(&x[b]);
  unsigned pown = xs1a[b];
  float h0 = bflo(pown);
  float h1 = bfhi(pown);
  float h2 = bf2f(xs1b[b]);
  float o0 = xv, o1 = xv * ri, o2 = xv * qi;

  // Stage this wave's 576 contiguous floats in LDS (write lane*9+k: stride-9
  // dwords, gcd(9,32)=1 -> 2 lanes/bank, conflict-free), then emit 144
  // aligned 16B nt-stores (1024B contiguous per instruction: full lines).
  float* ob = obuf[(threadIdx.x >> 6) & 3];
  ob[lane * 9 + 0] = o0;
  ob[lane * 9 + 1] = o1;
  ob[lane * 9 + 2] = o2;
  ob[lane * 9 + 3] = h0;
  ob[lane * 9 + 4] = h1;
  ob[lane * 9 + 5] = h2;
  ob[lane * 9 + 6] = A0 * dr - o0;
  ob[lane * 9 + 7] = A1 * dr - o1;
  ob[lane * 9 + 8] = A2 * dr - o2;
  __builtin_amdgcn_wave_barrier();   // wave-synchronous: own wave's region only
  vfloat4* op4 = (vfloat4*)(out + (size_t)w * 576);
#pragma unroll
  for (int it = 0; it < 2; ++it) {
    int idx = it * 64 + lane;
    vfloat4 v = *(const vfloat4*)&ob[idx * 4];
    __builtin_nontemporal_store(v, op4 + idx);
  }
  if (lane < 16) {
    int idx = 128 + lane;
    vfloat4 v = *(const vfloat4*)&ob[idx * 4];
    __builtin_nontemporal_store(v, op4 + idx);
  }
}

extern "C" void kernel_launch(void* const* d_in, const int* in_sizes, int n_in,
                              void* d_out, int out_size, void* d_ws, size_t ws_size,
                              hipStream_t stream) {
  const float* x   = (const float*)d_in[0];
  const float* deg = (const float*)d_in[1];
  const int*   row = (const int*)d_in[2];
  const int*   col = (const int*)d_in[3];
  float* out = (float*)d_out;

  int N = in_sizes[1];       // deg has N elements
  int E = in_sizes[2];       // row has E elements
  int NB = (N + 1023) / 1024;

  char* ws = (char*)d_ws;
  size_t off = 0;
  int* offsets = (int*)(ws + off); off = ws_align(off + (size_t)N * 4);
  int* cursor  = (int*)(ws + off); off = ws_align(off + (size_t)N * 4);
  int* partial = (int*)(ws + off); off = ws_align(off + (size_t)NB * 4);
  int* pscan   = (int*)(ws + off); off = ws_align(off + (size_t)NB * 4);
  int* csr     = (int*)(ws + off); off = ws_align(off + ((size_t)E + N) * 4);
  unsigned short* xb = (unsigned short*)(ws + off); off = ws_align(off + (size_t)N * 64 * 2);
  unsigned* xs1a = (unsigned*)(ws + off); off = ws_align(off + (size_t)N * 64 * 4);
  unsigned short* xs1b = (unsigned short*)(ws + off); off = ws_align(off + (size_t)N * 64 * 2);
  // total ~59 MB; harness ws confirmed larger

  k_blocksum<<<NB, 1024, 0, stream>>>(deg, partial, N);
  k_scanpartial<<<1, 128, 0, stream>>>(partial, pscan, NB);
  k_scanapply<<<NB, 1024, 0, stream>>>(deg, pscan, offsets, cursor, N);

  int n4 = N * 16;  // N*64/4 float4 groups
  int mx = (E > n4) ? E : n4;
  k_scatter_cvt<<<(mx + 255) / 256, 256, 0, stream>>>((const float4*)x,
      (uint2*)xb, row, col, cursor, csr, E, n4);

  int hopBlocks = (N + 3) / 4;   // 4 waves/block, 1 wave per node
  k_prop1<<<hopBlocks, 256, 0, stream>>>((const uint2*)xb, deg, offsets, cursor,
                                         csr, (uint4*)xs1a, (uint2*)xs1b, N);
  k_prop2<<<hopBlocks, 256, 0, stream>>>(x, deg, offsets, cursor, csr,
                                         (const uint4*)xs1a, (const uint2*)xs1b,
                                         xs1a, xs1b, out, N);
}

// Round 7
// 465.465 us; speedup vs baseline: 1.2996x; 1.0418x over previous
//
#include <hip/hip_runtime.h>

// NodeFeat: out[n,d,c] (c stride 1, d stride 9, n stride 576), c = hop*3 + part
//   hop0: x * {1, rsqrt(deg), sqrt(deg)}
//   hop1: (1/deg) * spmm(hop0)
//   hop2: (1/deg) * spmm(hop1) - hop0
// R7 (vs R6): MLP attack on the latency-bound prop loops (R4 counters: HBM
// 54%, VALU 27%, occ 75% -> nothing saturated -> dependent-chain latency).
//   - prop1/prop2 inner loops unrolled to 16 edges/pass: 12 independent VMEM
//     in flight (4 csr + 8 gathers) vs 6 before; most nodes (mean deg 16) do
//     1 full pass + 1 masked tail.
//   - epilogue loads (x[b], xs1a[b], xs1b[b], deg[w]) hoisted BEFORE the edge
//     loop -> overlap the gather phase instead of stalling after it.
//   - per-edge arithmetic identical to R6 (absmax must stay 0.125).

static inline size_t ws_align(size_t x) { return (x + 255) & ~(size_t)255; }

typedef float vfloat4 __attribute__((ext_vector_type(4)));

__device__ inline float bf2f(unsigned short s) {
  return __uint_as_float(((unsigned)s) << 16);
}
__device__ inline unsigned short f2bf(float f) {
  unsigned u = __float_as_uint(f);
  unsigned r = u + 0x7fff + ((u >> 16) & 1);   // round-to-nearest-even
  return (unsigned short)(r >> 16);
}
__device__ inline float bflo(unsigned p) { return __uint_as_float(p << 16); }
__device__ inline float bfhi(unsigned p) { return __uint_as_float(p & 0xffff0000u); }
__device__ inline unsigned packbf(float a, float b) {
  return (unsigned)f2bf(a) | ((unsigned)f2bf(b) << 16);
}
__device__ inline float sel4(float u0, float u1, float u2, float u3, int k) {
  float a = (k & 1) ? u1 : u0;
  float b = (k & 1) ? u3 : u2;
  return (k & 2) ? b : a;
}

// per-1024-chunk sums of (int)deg -> partial
__global__ __launch_bounds__(1024) void k_blocksum(const float* __restrict__ deg,
                                                   int* __restrict__ partial, int N) {
  __shared__ int wsum[16];
  int t = threadIdx.x;
  int idx = blockIdx.x * 1024 + t;
  int v = (idx < N) ? (int)(deg[idx] + 0.5f) : 0;
  for (int off = 32; off; off >>= 1) v += __shfl_down(v, off, 64);
  if ((t & 63) == 0) wsum[t >> 6] = v;
  __syncthreads();
  if (t == 0) {
    int s = 0;
#pragma unroll
    for (int k = 0; k < 16; ++k) s += wsum[k];
    partial[blockIdx.x] = s;
  }
}

__global__ void k_scanpartial(const int* __restrict__ partial,
                              int* __restrict__ pscan, int NB) {
  __shared__ int buf[1024];
  int t = threadIdx.x;
  for (int k = t; k < NB; k += blockDim.x) buf[k] = partial[k];
  __syncthreads();
  if (t == 0) {
    int run = 0;
    for (int k = 0; k < NB; ++k) { int v = buf[k]; buf[k] = run; run += v; }
  }
  __syncthreads();
  for (int k = t; k < NB; k += blockDim.x) pscan[k] = buf[k];
}

__global__ __launch_bounds__(1024) void k_scanapply(const float* __restrict__ deg,
    const int* __restrict__ pscan, int* __restrict__ offsets,
    int* __restrict__ cursor, int N) {
  __shared__ int wsum[16];
  int t = threadIdx.x, lane = t & 63, wv = t >> 6;
  int idx = blockIdx.x * 1024 + t;
  int v = (idx < N) ? (int)(deg[idx] + 0.5f) : 0;
  int x = v;
#pragma unroll
  for (int off = 1; off < 64; off <<= 1) {
    int y = __shfl_up(x, off, 64);
    if (lane >= off) x += y;
  }
  if (lane == 63) wsum[wv] = x;
  __syncthreads();
  if (t == 0) {
    int run = 0;
#pragma unroll
    for (int k = 0; k < 16; ++k) { int s = wsum[k]; wsum[k] = run; run += s; }
  }
  __syncthreads();
  int excl = pscan[blockIdx.x] + wsum[wv] + x - v;
  if (idx < N) { offsets[idx] = excl; cursor[idx] = excl; }
}

// fused: cvt (x fp32 -> bf16 xb, i < n4) + scatter (e < E)
__global__ __launch_bounds__(256) void k_scatter_cvt(const float4* __restrict__ x4,
    uint2* __restrict__ xb2, const int* __restrict__ row,
    const int* __restrict__ col, int* __restrict__ cursor,
    int* __restrict__ csr, int E, int n4) {
  int i = blockIdx.x * 256 + threadIdx.x;
  if (i < n4) {
    float4 v = x4[i];
    uint2 p;
    p.x = packbf(v.x, v.y);
    p.y = packbf(v.z, v.w);
    xb2[i] = p;
  }
  if (i < E) {
    int r = row[i];
    int pos = atomicAdd(&cursor[r], 1);
    csr[pos] = col[i];
  }
}
// After k_scatter_cvt, cursor[i] == offsets[i] + true_count[i]  (used as `ends`).

// hop1: one wave per node; 4 groups of 16 lanes each own one edge; each lane
// covers 4 features. 16 edges per pass (12 independent VMEM in flight).
// Writes packed xs1 (uint4: h0|h1, uint2: h2).
__global__ __launch_bounds__(256) void k_prop1(const uint2* __restrict__ xb2,
    const float* __restrict__ deg, const int* __restrict__ offsets,
    const int* __restrict__ ends, const int* __restrict__ csr,
    uint4* __restrict__ xs1a4, uint2* __restrict__ xs1b2, int N) {
  int w = (blockIdx.x * 256 + threadIdx.x) >> 6;
  int lane = threadIdx.x & 63;
  if (w >= N) return;
  int q = lane & 15;
  int g = lane >> 4;
  int beg = offsets[w];
  int end = ends[w];
  float degw = deg[w];                           // hoisted epilogue load
  float s0[4] = {0.f, 0.f, 0.f, 0.f};
  float s1[4] = {0.f, 0.f, 0.f, 0.f};
  float s2[4] = {0.f, 0.f, 0.f, 0.f};
  int base = beg;
  for (; base + 16 <= end; base += 16) {         // 16 edges per pass
    int j0 = csr[base + g];
    int j1 = csr[base + 4 + g];
    int j2 = csr[base + 8 + g];
    int j3 = csr[base + 12 + g];
    uint2 v0 = xb2[(size_t)j0 * 16 + q];
    uint2 v1 = xb2[(size_t)j1 * 16 + q];
    uint2 v2 = xb2[(size_t)j2 * 16 + q];
    uint2 v3 = xb2[(size_t)j3 * 16 + q];
    float d0 = deg[j0], d1 = deg[j1], d2 = deg[j2], d3 = deg[j3];
    float r0 = rsqrtf(d0), r1 = rsqrtf(d1), r2 = rsqrtf(d2), r3 = rsqrtf(d3);
    float p0 = d0 * r0, p1 = d1 * r1, p2 = d2 * r2, p3 = d3 * r3;
    float f00 = bflo(v0.x), f01 = bfhi(v0.x), f02 = bflo(v0.y), f03 = bfhi(v0.y);
    float f10 = bflo(v1.x), f11 = bfhi(v1.x), f12 = bflo(v1.y), f13 = bfhi(v1.y);
    float f20 = bflo(v2.x), f21 = bfhi(v2.x), f22 = bflo(v2.y), f23 = bfhi(v2.y);
    float f30 = bflo(v3.x), f31 = bfhi(v3.x), f32 = bflo(v3.y), f33 = bfhi(v3.y);
    s0[0] += (f00 + f10) + (f20 + f30);
    s0[1] += (f01 + f11) + (f21 + f31);
    s0[2] += (f02 + f12) + (f22 + f32);
    s0[3] += (f03 + f13) + (f23 + f33);
    s1[0] = fmaf(f30, r3, fmaf(f20, r2, fmaf(f10, r1, fmaf(f00, r0, s1[0]))));
    s1[1] = fmaf(f31, r3, fmaf(f21, r2, fmaf(f11, r1, fmaf(f01, r0, s1[1]))));
    s1[2] = fmaf(f32, r3, fmaf(f22, r2, fmaf(f12, r1, fmaf(f02, r0, s1[2]))));
    s1[3] = fmaf(f33, r3, fmaf(f23, r2, fmaf(f13, r1, fmaf(f03, r0, s1[3]))));
    s2[0] = fmaf(f30, p3, fmaf(f20, p2, fmaf(f10, p1, fmaf(f00, p0, s2[0]))));
    s2[1] = fmaf(f31, p3, fmaf(f21, p2, fmaf(f11, p1, fmaf(f01, p0, s2[1]))));
    s2[2] = fmaf(f32, p3, fmaf(f22, p2, fmaf(f12, p1, fmaf(f02, p0, s2[2]))));
    s2[3] = fmaf(f33, p3, fmaf(f23, p2, fmaf(f13, p1, fmaf(f03, p0, s2[3]))));
  }
  if (base < end) {                               // masked tail, up to 15 edges
    int e0 = base + g, e1 = base + 4 + g, e2 = base + 8 + g, e3 = base + 12 + g;
    bool b0 = e0 < end, b1 = e1 < end, b2 = e2 < end, b3 = e3 < end;
    int j0 = csr[b0 ? e0 : beg];
    int j1 = csr[b1 ? e1 : beg];
    int j2 = csr[b2 ? e2 : beg];
    int j3 = csr[b3 ? e3 : beg];
    uint2 v0 = xb2[(size_t)j0 * 16 + q];
    uint2 v1 = xb2[(size_t)j1 * 16 + q];
    uint2 v2 = xb2[(size_t)j2 * 16 + q];
    uint2 v3 = xb2[(size_t)j3 * 16 + q];
    float d0 = deg[j0], d1 = deg[j1], d2 = deg[j2], d3 = deg[j3];
    float m0 = b0 ? 1.f : 0.f, m1 = b1 ? 1.f : 0.f;
    float m2 = b2 ? 1.f : 0.f, m3 = b3 ? 1.f : 0.f;
    float r0 = rsqrtf(d0) * m0, r1 = rsqrtf(d1) * m1;
    float r2 = rsqrtf(d2) * m2, r3 = rsqrtf(d3) * m3;
    float p0 = d0 * r0, p1 = d1 * r1, p2 = d2 * r2, p3 = d3 * r3;
    float f00 = bflo(v0.x), f01 = bfhi(v0.x), f02 = bflo(v0.y), f03 = bfhi(v0.y);
    float f10 = bflo(v1.x), f11 = bfhi(v1.x), f12 = bflo(v1.y), f13 = bfhi(v1.y);
    float f20 = bflo(v2.x), f21 = bfhi(v2.x), f22 = bflo(v2.y), f23 = bfhi(v2.y);
    float f30 = bflo(v3.x), f31 = bfhi(v3.x), f32 = bflo(v3.y), f33 = bfhi(v3.y);
    s0[0] = fmaf(f30, m3, fmaf(f20, m2, fmaf(f10, m1, fmaf(f00, m0, s0[0]))));
    s0[1] = fmaf(f31, m3, fmaf(f21, m2, fmaf(f11, m1, fmaf(f01, m0, s0[1]))));
    s0[2] = fmaf(f32, m3, fmaf(f22, m2, fmaf(f12, m1, fmaf(f02, m0, s0[2]))));
    s0[3] = fmaf(f33, m3, fmaf(f23, m2, fmaf(f13, m1, fmaf(f03, m0, s0[3]))));
    s1[0] = fmaf(f30, r3, fmaf(f20, r2, fmaf(f10, r1, fmaf(f00, r0, s1[0]))));
    s1[1] = fmaf(f31, r3, fmaf(f21, r2, fmaf(f11, r1, fmaf(f01, r0, s1[1]))));
    s1[2] = fmaf(f32, r3, fmaf(f22, r2, fmaf(f12, r1, fmaf(f02, r0, s1[2]))));
    s1[3] = fmaf(f33, r3, fmaf(f23, r2, fmaf(f13, r1, fmaf(f03, r0, s1[3]))));
    s2[0] = fmaf(f30, p3, fmaf(f20, p2, fmaf(f10, p1, fmaf(f00, p0, s2[0]))));
    s2[1] = fmaf(f31, p3, fmaf(f21, p2, fmaf(f11, p1, fmaf(f01, p0, s2[1]))));
    s2[2] = fmaf(f32, p3, fmaf(f22, p2, fmaf(f12, p1, fmaf(f02, p0, s2[2]))));
    s2[3] = fmaf(f33, p3, fmaf(f23, p2, fmaf(f13, p1, fmaf(f03, p0, s2[3]))));
  }
#pragma unroll
  for (int k = 0; k < 4; ++k) {                   // cross-group reduce
    s0[k] += __shfl_xor(s0[k], 16, 64); s0[k] += __shfl_xor(s0[k], 32, 64);
    s1[k] += __shfl_xor(s1[k], 16, 64); s1[k] += __shfl_xor(s1[k], 32, 64);
    s2[k] += __shfl_xor(s2[k], 16, 64); s2[k] += __shfl_xor(s2[k], 32, 64);
  }
  if (g == 0) {
    float dr = 1.0f / degw;
    uint4 A;
    A.x = packbf(s0[0] * dr, s1[0] * dr);
    A.y = packbf(s0[1] * dr, s1[1] * dr);
    A.z = packbf(s0[2] * dr, s1[2] * dr);
    A.w = packbf(s0[3] * dr, s1[3] * dr);
    uint2 B;
    B.x = (unsigned)f2bf(s2[0] * dr) | ((unsigned)f2bf(s2[1] * dr) << 16);
    B.y = (unsigned)f2bf(s2[2] * dr) | ((unsigned)f2bf(s2[3] * dr) << 16);
    xs1a4[(size_t)w * 16 + q] = A;
    xs1b2[(size_t)w * 16 + q] = B;
  }
}

// hop2 + epilogue: 16-edges-per-pass gather of packed xs1, cross-group reduce,
// redistribute to lane=d, LDS-stage 576 floats, 144 aligned 16B nt-stores.
__global__ __launch_bounds__(256) void k_prop2(const float* __restrict__ x,
    const float* __restrict__ deg, const int* __restrict__ offsets,
    const int* __restrict__ ends, const int* __restrict__ csr,
    const uint4* __restrict__ xs1a4, const uint2* __restrict__ xs1b2,
    const unsigned* __restrict__ xs1a, const unsigned short* __restrict__ xs1b,
    float* __restrict__ out, int N) {
  __shared__ __align__(16) float obuf[4][576];
  int w = (blockIdx.x * 256 + threadIdx.x) >> 6;
  int lane = threadIdx.x & 63;
  if (w >= N) return;
  int q = lane & 15;
  int g = lane >> 4;
  int beg = offsets[w];
  int end = ends[w];
  // hoisted epilogue loads: overlap the gather loop
  size_t b = (size_t)w * 64 + lane;
  float xv = __builtin_nontemporal_load(&x[b]);
  unsigned pown = xs1a[b];
  unsigned short ownb = xs1b[b];
  float degi = deg[w];
  float a0[4] = {0.f, 0.f, 0.f, 0.f};
  float a1[4] = {0.f, 0.f, 0.f, 0.f};
  float a2[4] = {0.f, 0.f, 0.f, 0.f};
  int base = beg;
  for (; base + 16 <= end; base += 16) {          // 16 edges per pass
    int j0 = csr[base + g];
    int j1 = csr[base + 4 + g];
    int j2 = csr[base + 8 + g];
    int j3 = csr[base + 12 + g];
    uint4 pa0 = xs1a4[(size_t)j0 * 16 + q];
    uint4 pa1 = xs1a4[(size_t)j1 * 16 + q];
    uint4 pa2 = xs1a4[(size_t)j2 * 16 + q];
    uint4 pa3 = xs1a4[(size_t)j3 * 16 + q];
    uint2 pb0 = xs1b2[(size_t)j0 * 16 + q];
    uint2 pb1 = xs1b2[(size_t)j1 * 16 + q];
    uint2 pb2 = xs1b2[(size_t)j2 * 16 + q];
    uint2 pb3 = xs1b2[(size_t)j3 * 16 + q];
    a0[0] += (bflo(pa0.x) + bflo(pa1.x)) + (bflo(pa2.x) + bflo(pa3.x));
    a0[1] += (bflo(pa0.y) + bflo(pa1.y)) + (bflo(pa2.y) + bflo(pa3.y));
    a0[2] += (bflo(pa0.z) + bflo(pa1.z)) + (bflo(pa2.z) + bflo(pa3.z));
    a0[3] += (bflo(pa0.w) + bflo(pa1.w)) + (bflo(pa2.w) + bflo(pa3.w));
    a1[0] += (bfhi(pa0.x) + bfhi(pa1.x)) + (bfhi(pa2.x) + bfhi(pa3.x));
    a1[1] += (bfhi(pa0.y) + bfhi(pa1.y)) + (bfhi(pa2.y) + bfhi(pa3.y));
    a1[2] += (bfhi(pa0.z) + bfhi(pa1.z)) + (bfhi(pa2.z) + bfhi(pa3.z));
    a1[3] += (bfhi(pa0.w) + bfhi(pa1.w)) + (bfhi(pa2.w) + bfhi(pa3.w));
    a2[0] += (bflo(pb0.x) + bflo(pb1.x)) + (bflo(pb2.x) + bflo(pb3.x));
    a2[1] += (bfhi(pb0.x) + bfhi(pb1.x)) + (bfhi(pb2.x) + bfhi(pb3.x));
    a2[2] += (bflo(pb0.y) + bflo(pb1.y)) + (bflo(pb2.y) + bflo(pb3.y));
    a2[3] += (bfhi(pb0.y) + bfhi(pb1.y)) + (bfhi(pb2.y) + bfhi(pb3.y));
  }
  if (base < end) {                                // masked tail, up to 15 edges
    int e0 = base + g, e1 = base + 4 + g, e2 = base + 8 + g, e3 = base + 12 + g;
    bool b0 = e0 < end, b1 = e1 < end, b2 = e2 < end, b3 = e3 < end;
    int j0 = csr[b0 ? e0 : beg];
    int j1 = csr[b1 ? e1 : beg];
    int j2 = csr[b2 ? e2 : beg];
    int j3 = csr[b3 ? e3 : beg];
    uint4 pa0 = xs1a4[(size_t)j0 * 16 + q];
    uint4 pa1 = xs1a4[(size_t)j1 * 16 + q];
    uint4 pa2 = xs1a4[(size_t)j2 * 16 + q];
    uint4 pa3 = xs1a4[(size_t)j3 * 16 + q];
    uint2 pb0 = xs1b2[(size_t)j0 * 16 + q];
    uint2 pb1 = xs1b2[(size_t)j1 * 16 + q];
    uint2 pb2 = xs1b2[(size_t)j2 * 16 + q];
    uint2 pb3 = xs1b2[(size_t)j3 * 16 + q];
    float m0 = b0 ? 1.f : 0.f, m1 = b1 ? 1.f : 0.f;
    float m2 = b2 ? 1.f : 0.f, m3 = b3 ? 1.f : 0.f;
    a0[0] = fmaf(bflo(pa3.x), m3, fmaf(bflo(pa2.x), m2,
             fmaf(bflo(pa1.x), m1, fmaf(bflo(pa0.x), m0, a0[0]))));
    a0[1] = fmaf(bflo(pa3.y), m3, fmaf(bflo(pa2.y), m2,
             fmaf(bflo(pa1.y), m1, fmaf(bflo(pa0.y), m0, a0[1]))));
    a0[2] = fmaf(bflo(pa3.z), m3, fmaf(bflo(pa2.z), m2,
             fmaf(bflo(pa1.z), m1, fmaf(bflo(pa0.z), m0, a0[2]))));
    a0[3] = fmaf(bflo(pa3.w), m3, fmaf(bflo(pa2.w), m2,
             fmaf(bflo(pa1.w), m1, fmaf(bflo(pa0.w), m0, a0[3]))));
    a1[0] = fmaf(bfhi(pa3.x), m3, fmaf(bfhi(pa2.x), m2,
             fmaf(bfhi(pa1.x), m1, fmaf(bfhi(pa0.x), m0, a1[0]))));
    a1[1] = fmaf(bfhi(pa3.y), m3, fmaf(bfhi(pa2.y), m2,
             fmaf(bfhi(pa1.y), m1, fmaf(bfhi(pa0.y), m0, a1[1]))));
    a1[2] = fmaf(bfhi(pa3.z), m3, fmaf(bfhi(pa2.z), m2,
             fmaf(bfhi(pa1.z), m1, fmaf(bfhi(pa0.z), m0, a1[2]))));
    a1[3] = fmaf(bfhi(pa3.w), m3, fmaf(bfhi(pa2.w), m2,
             fmaf(bfhi(pa1.w), m1, fmaf(bfhi(pa0.w), m0, a1[3]))));
    a2[0] = fmaf(bflo(pb3.x), m3, fmaf(bflo(pb2.x), m2,
             fmaf(bflo(pb1.x), m1, fmaf(bflo(pb0.x), m0, a2[0]))));
    a2[1] = fmaf(bfhi(pb3.x), m3, fmaf(bfhi(pb2.x), m2,
             fmaf(bfhi(pb1.x), m1, fmaf(bfhi(pb0.x), m0, a2[1]))));
    a2[2] = fmaf(bflo(pb3.y), m3, fmaf(bflo(pb2.y), m2,
             fmaf(bflo(pb1.y), m1, fmaf(bflo(pb0.y), m0, a2[2]))));
    a2[3] = fmaf(bfhi(pb3.y), m3, fmaf(bfhi(pb2.y), m2,
             fmaf(bfhi(pb1.y), m1, fmaf(bfhi(pb0.y), m0, a2[3]))));
  }
#pragma unroll
  for (int k = 0; k < 4; ++k) {
    a0[k] += __shfl_xor(a0[k], 16, 64); a0[k] += __shfl_xor(a0[k], 32, 64);
    a1[k] += __shfl_xor(a1[k], 16, 64); a1[k] += __shfl_xor(a1[k], 32, 64);
    a2[k] += __shfl_xor(a2[k], 16, 64); a2[k] += __shfl_xor(a2[k], 32, 64);
  }
  // redistribute: lane d needs sums for feature d (held at lane d>>2, slot d&3)
  int src = lane >> 2;
  int k = lane & 3;
  float A0 = sel4(__shfl(a0[0], src, 64), __shfl(a0[1], src, 64),
                  __shfl(a0[2], src, 64), __shfl(a0[3], src, 64), k);
  float A1 = sel4(__shfl(a1[0], src, 64), __shfl(a1[1], src, 64),
                  __shfl(a1[2], src, 64), __shfl(a1[3], src, 64), k);
  float A2 = sel4(__shfl(a2[0], src, 64), __shfl(a2[1], src, 64),
                  __shfl(a2[2], src, 64), __shfl(a2[3], src, 64), k);
  float dr = 1.0f / degi;
  float ri = rsqrtf(degi);
  float qi = degi * ri;
  float h0 = bflo(pown);
  float h1 = bfhi(pown);
  float h2 = bf2f(ownb);
  float o0 = xv, o1 = xv * ri, o2 = xv * qi;

  // Stage this wave's 576 contiguous floats in LDS (write lane*9+k: stride-9
  // dwords, gcd(9,32)=1 -> 2 lanes/bank, conflict-free), then emit 144
  // aligned 16B nt-stores (1024B contiguous per instruction: full lines).
  float* ob = obuf[(threadIdx.x >> 6) & 3];
  ob[lane * 9 + 0] = o0;
  ob[lane * 9 + 1] = o1;
  ob[lane * 9 + 2] = o2;
  ob[lane * 9 + 3] = h0;
  ob[lane * 9 + 4] = h1;
  ob[lane * 9 + 5] = h2;
  ob[lane * 9 + 6] = A0 * dr - o0;
  ob[lane * 9 + 7] = A1 * dr - o1;
  ob[lane * 9 + 8] = A2 * dr - o2;
  __builtin_amdgcn_wave_barrier();   // wave-synchronous: own wave's region only
  vfloat4* op4 = (vfloat4*)(out + (size_t)w * 576);
#pragma unroll
  for (int it = 0; it < 2; ++it) {
    int idx = it * 64 + lane;
    vfloat4 v = *(const vfloat4*)&ob[idx * 4];
    __builtin_nontemporal_store(v, op4 + idx);
  }
  if (lane < 16) {
    int idx = 128 + lane;
    vfloat4 v = *(const vfloat4*)&ob[idx * 4];
    __builtin_nontemporal_store(v, op4 + idx);
  }
}

extern "C" void kernel_launch(void* const* d_in, const int* in_sizes, int n_in,
                              void* d_out, int out_size, void* d_ws, size_t ws_size,
                              hipStream_t stream) {
  const float* x   = (const float*)d_in[0];
  const float* deg = (const float*)d_in[1];
  const int*   row = (const int*)d_in[2];
  const int*   col = (const int*)d_in[3];
  float* out = (float*)d_out;

  int N = in_sizes[1];       // deg has N elements
  int E = in_sizes[2];       // row has E elements
  int NB = (N + 1023) / 1024;

  char* ws = (char*)d_ws;
  size_t off = 0;
  int* offsets = (int*)(ws + off); off = ws_align(off + (size_t)N * 4);
  int* cursor  = (int*)(ws + off); off = ws_align(off + (size_t)N * 4);
  int* partial = (int*)(ws + off); off = ws_align(off + (size_t)NB * 4);
  int* pscan   = (int*)(ws + off); off = ws_align(off + (size_t)NB * 4);
  int* csr     = (int*)(ws + off); off = ws_align(off + ((size_t)E + N) * 4);
  unsigned short* xb = (unsigned short*)(ws + off); off = ws_align(off + (size_t)N * 64 * 2);
  unsigned* xs1a = (unsigned*)(ws + off); off = ws_align(off + (size_t)N * 64 * 4);
  unsigned short* xs1b = (unsigned short*)(ws + off); off = ws_align(off + (size_t)N * 64 * 2);
  // total ~59 MB; harness ws confirmed larger

  k_blocksum<<<NB, 1024, 0, stream>>>(deg, partial, N);
  k_scanpartial<<<1, 128, 0, stream>>>(partial, pscan, NB);
  k_scanapply<<<NB, 1024, 0, stream>>>(deg, pscan, offsets, cursor, N);

  int n4 = N * 16;  // N*64/4 float4 groups
  int mx = (E > n4) ? E : n4;
  k_scatter_cvt<<<(mx + 255) / 256, 256, 0, stream>>>((const float4*)x,
      (uint2*)xb, row, col, cursor, csr, E, n4);

  int hopBlocks = (N + 3) / 4;   // 4 waves/block, 1 wave per node
  k_prop1<<<hopBlocks, 256, 0, stream>>>((const uint2*)xb, deg, offsets, cursor,
                                         csr, (uint4*)xs1a, (uint2*)xs1b, N);
  k_prop2<<<hopBlocks, 256, 0, stream>>>(x, deg, offsets, cursor, csr,
                                         (const uint4*)xs1a, (const uint2*)xs1b,
                                         xs1a, xs1b, out, N);
}